// Round 3
// baseline (336.903 us; speedup 1.0000x reference)
//
#include <hip/hip_runtime.h>

// CutOut fused copy+mask: images (64,512,512,3) f32 -> out, zeroing a
// 50x50 box (clipped) per batch centered at (center_h[b], center_w[b]).
// Output tail: labels (64) as f32.
//
// Memory-bound: 201 MB read + 201 MB write. Target = m13 float4-copy
// ceiling (6.29 TB/s combined -> ~64 us for 402.7 MB).
//
// Shape: grid-stride float4 copy, 2048 blocks x 256 threads
// (8 WG/CU -> 32 waves/CU), 24 iterations/thread, lane-contiguous
// 16B/lane. Mask is computed branchlessly per vec (R0 style): VALUBusy
// was 5%, VMEM-issue trivial -- streaming efficiency is the only thing
// that matters here.
//
// Session lessons:
//  R1: __builtin_nontemporal_store = -8.5us (bypasses L2 write-combine).
//  R2: 4 f4/thread @16KB stride + fat blocks = -9us vs R0's sequential
//      one-vec-per-thread stream. Keep accesses purely sequential.

#define HALF   25
#define BATCH  64
#define IMG_H  512
#define IMG_W  512
#define IMG_C  3
#define N_PIX  (BATCH * IMG_H * IMG_W)            // 16,777,216
#define N_ELEM ((size_t)N_PIX * IMG_C)            // 50,331,648
#define N_VEC  (N_ELEM / 4)                       // 12,582,912 float4s

#define NBLOCKS 2048
#define NTHREADS 256
#define STRIDE  (NBLOCKS * NTHREADS)              // 524288
#define NITER   (N_VEC / STRIDE)                  // 24, exact

typedef float f4 __attribute__((ext_vector_type(4)));

__device__ __forceinline__ bool inbox(unsigned p,
                                      const int* __restrict__ ch,
                                      const int* __restrict__ cw) {
    const int w = (int)(p & (IMG_W - 1));
    const int h = (int)((p >> 9) & (IMG_H - 1));
    const int b = (int)(p >> 18);
    const int chb = ch[b];      // same addr across most of the wave -> L1 broadcast
    const int cwb = cw[b];
    return (h >= chb - HALF) & (h < chb + HALF) &
           (w >= cwb - HALF) & (w < cwb + HALF);
}

__global__ __launch_bounds__(NTHREADS) void cutout_fused(
    const f4* __restrict__ in,
    f4* __restrict__ out,
    const int* __restrict__ center_h,
    const int* __restrict__ center_w,
    const int* __restrict__ labels,
    float* __restrict__ out_labels)
{
    if (blockIdx.x == 0 && threadIdx.x < BATCH) {
        out_labels[threadIdx.x] = (float)labels[threadIdx.x];
    }

    unsigned vid = blockIdx.x * (unsigned)NTHREADS + threadIdx.x;

    #pragma unroll 4
    for (int it = 0; it < NITER; ++it, vid += STRIDE) {
        f4 v = in[vid];

        const unsigned idx4 = vid * 4u;              // element base, < 2^26
        const unsigned pi   = idx4 / 3u;             // pixel of element 0 (magic-mul)
        const unsigned rem  = idx4 - pi * 3u;        // channel of element 0

        // Elements 0..3 live in pixel pi or pi+1 (pi+1 <= N_PIX-1 always):
        const bool m0 = inbox(pi,     center_h, center_w);
        const bool m1 = inbox(pi + 1, center_h, center_w);

        const bool me0 = m0;
        const bool me1 = (rem >= 2) ? m1 : m0;
        const bool me2 = (rem >= 1) ? m1 : m0;
        const bool me3 = m1;

        if (me0) v[0] = 0.0f;
        if (me1) v[1] = 0.0f;
        if (me2) v[2] = 0.0f;
        if (me3) v[3] = 0.0f;

        out[vid] = v;
    }
}

extern "C" void kernel_launch(void* const* d_in, const int* in_sizes, int n_in,
                              void* d_out, int out_size, void* d_ws, size_t ws_size,
                              hipStream_t stream) {
    const float* images   = (const float*)d_in[0];
    const int*   labels   = (const int*)  d_in[1];
    const int*   center_h = (const int*)  d_in[2];
    const int*   center_w = (const int*)  d_in[3];
    float* out = (float*)d_out;

    cutout_fused<<<NBLOCKS, NTHREADS, 0, stream>>>(
        (const f4*)images, (f4*)out,
        center_h, center_w, labels, out + N_ELEM);
}

// Round 4
// 332.158 us; speedup vs baseline: 1.0143x; 1.0143x over previous
//
#include <hip/hip_runtime.h>

// CutOut via split copy + box-zero:
//   1) hipMemcpyAsync D2D: images -> out (201.3 MB payload). The
//      runtime blit/SDMA path is the fastest mover of bytes on this
//      chip (fills hit 6.6 TB/s; our best hand kernel 5.2 TB/s).
//   2) zero_boxes kernel: zero the clipped 50x50x3 box per image
//      (<= 1.9 MB of writes total) and emit labels as f32.
// Stream order makes (2) run after (1).
//
// Session lessons:
//  R1: nontemporal stores  -> -8.5us (bypass L2 write-combine).
//  R2: 4xf4/thread strided -> -9us vs sequential one-vec-per-thread.
//  R3: 2048-block grid-stride copy -> -16us vs R0. Hand-written copy
//      shapes plateau at ~5.2 TB/s; delegate the copy to the runtime.

#define HALF   25
#define BATCH  64
#define IMG_H  512
#define IMG_W  512
#define IMG_C  3
#define ELEM_PER_IMG (IMG_H * IMG_W * IMG_C)            // 786432
#define N_ELEM ((size_t)BATCH * ELEM_PER_IMG)           // 50,331,648

// One block per image. Zero out[b, r0..r1, c0..c1, :] and write labels.
__global__ __launch_bounds__(256) void zero_boxes(
    float* __restrict__ out,
    const int* __restrict__ center_h,
    const int* __restrict__ center_w,
    const int* __restrict__ labels,
    float* __restrict__ out_labels)
{
    const int b = blockIdx.x;

    if (b == 0 && threadIdx.x < BATCH) {
        out_labels[threadIdx.x] = (float)labels[threadIdx.x];
    }

    const int chb = center_h[b];                 // block-uniform -> s_load
    const int cwb = center_w[b];

    const int r0 = max(chb - HALF, 0);
    const int r1 = min(chb + HALF, IMG_H);       // exclusive
    const int c0 = max(cwb - HALF, 0);
    const int c1 = min(cwb + HALF, IMG_W);       // exclusive

    const int row_elems = (c1 - c0) * IMG_C;     // <= 150 floats per row
    const int wid  = (int)(threadIdx.x >> 6);    // 4 waves
    const int lane = (int)(threadIdx.x & 63);

    float* img = out + (size_t)b * ELEM_PER_IMG;

    // Each wave takes rows r0+wid, r0+wid+4, ... ; lanes stride the row.
    for (int r = r0 + wid; r < r1; r += 4) {
        float* row = img + ((size_t)r * IMG_W + c0) * IMG_C;
        for (int i = lane; i < row_elems; i += 64) {
            row[i] = 0.0f;
        }
    }
}

extern "C" void kernel_launch(void* const* d_in, const int* in_sizes, int n_in,
                              void* d_out, int out_size, void* d_ws, size_t ws_size,
                              hipStream_t stream) {
    const float* images   = (const float*)d_in[0];
    const int*   labels   = (const int*)  d_in[1];
    const int*   center_h = (const int*)  d_in[2];
    const int*   center_w = (const int*)  d_in[3];
    float* out = (float*)d_out;

    // Bulk byte-move on the runtime's tuned path.
    hipMemcpyAsync(out, images, N_ELEM * sizeof(float),
                   hipMemcpyDeviceToDevice, stream);

    // Then patch the boxes + labels (ordered on the same stream).
    zero_boxes<<<BATCH, 256, 0, stream>>>(
        out, center_h, center_w, labels, out + N_ELEM);
}

// Round 5
// 322.086 us; speedup vs baseline: 1.0460x; 1.0313x over previous
//
#include <hip/hip_runtime.h>

// CutOut fused copy+mask: images (64,512,512,3) f32 -> out, zeroing a
// 50x50 box (clipped) per batch centered at (center_h[b], center_w[b]).
// Output tail: labels (64) as f32.
//
// Memory-bound: 201 MB read + 201 MB write. One float4 per thread.
// 4 consecutive floats span at most 2 pixels (C=3): two box tests,
// per-element select. H=W=512 are pow2 -> shifts; /3 is a magic-mul.
//
// This is the session-best shape (321.5 us total; kernel ~77 us =
// 5.2 TB/s mixed stream). Tested-and-rejected alternatives:
//  R1: +nontemporal stores          -> 339.2 (NT bypasses L2 write-combine)
//  R2: 4xf4/thread + uniform s_load -> 330.8 (strided stream loses)
//  R3: 2048-block grid-stride       -> 336.9
//  R4: hipMemcpyAsync + box-zero    -> 332.2 (runtime blit no faster)
// Keep the one-vec-per-thread, launch-order-sequential stream.

#define HALF   25
#define BATCH  64
#define IMG_H  512
#define IMG_W  512
#define IMG_C  3
#define N_PIX  (BATCH * IMG_H * IMG_W)            // 16,777,216
#define N_ELEM ((size_t)N_PIX * IMG_C)            // 50,331,648
#define N_VEC  (N_ELEM / 4)                       // 12,582,912 float4s

__device__ __forceinline__ bool inbox(unsigned p,
                                      const int* __restrict__ ch,
                                      const int* __restrict__ cw) {
    const int w = (int)(p & (IMG_W - 1));
    const int h = (int)((p >> 9) & (IMG_H - 1));
    const int b = (int)(p >> 18);
    const int chb = ch[b];      // wave-uniform -> L1 broadcast
    const int cwb = cw[b];
    return (h >= chb - HALF) & (h < chb + HALF) &
           (w >= cwb - HALF) & (w < cwb + HALF);
}

__global__ __launch_bounds__(256) void cutout_fused(
    const float4* __restrict__ in,
    float4* __restrict__ out,
    const int* __restrict__ center_h,
    const int* __restrict__ center_w,
    const int* __restrict__ labels,
    float* __restrict__ out_labels)
{
    const unsigned vid = blockIdx.x * 256u + threadIdx.x;   // < N_VEC < 2^24

    if (blockIdx.x == 0 && threadIdx.x < BATCH) {
        out_labels[threadIdx.x] = (float)labels[threadIdx.x];
    }

    float4 v = in[vid];

    const unsigned idx4 = vid * 4u;              // element base, < 2^26
    const unsigned pi   = idx4 / 3u;             // pixel of element 0 (magic-mul)
    const unsigned rem  = idx4 - pi * 3u;        // channel of element 0

    // Elements 0..3 live in pixel pi or pi+1:
    //   e0 -> pi;  e1 -> (rem>=2 ? pi+1 : pi);  e2 -> (rem>=1 ? pi+1 : pi);  e3 -> pi+1
    const bool m0 = inbox(pi,     center_h, center_w);
    const bool m1 = inbox(pi + 1, center_h, center_w);  // pi+1 <= N_PIX-1 always

    const bool me0 = m0;
    const bool me1 = (rem >= 2) ? m1 : m0;
    const bool me2 = (rem >= 1) ? m1 : m0;
    const bool me3 = m1;

    if (me0) v.x = 0.0f;
    if (me1) v.y = 0.0f;
    if (me2) v.z = 0.0f;
    if (me3) v.w = 0.0f;

    out[vid] = v;
}

extern "C" void kernel_launch(void* const* d_in, const int* in_sizes, int n_in,
                              void* d_out, int out_size, void* d_ws, size_t ws_size,
                              hipStream_t stream) {
    const float* images   = (const float*)d_in[0];
    const int*   labels   = (const int*)  d_in[1];
    const int*   center_h = (const int*)  d_in[2];
    const int*   center_w = (const int*)  d_in[3];
    float* out = (float*)d_out;

    const unsigned nblocks = N_VEC / 256;        // 49152, exact
    cutout_fused<<<nblocks, 256, 0, stream>>>(
        (const float4*)images, (float4*)out,
        center_h, center_w, labels, out + N_ELEM);
}